// Round 9
// baseline (717.144 us; speedup 1.0000x reference)
//
#include <hip/hip_runtime.h>
#include <hip/hip_bf16.h>

// GraphSAGE 3-layer forward, MI355X. Round 14: persistent mega-kernel, hang-proofed.
//  R13 hung (container killed): grid=1024 assumed 4 blocks/CU co-residency from
//  static arithmetic. Fixes, with phase math UNCHANGED (R12-verbatim):
//   1) grid = hipOccupancyMaxActiveBlocksPerMultiprocessor x multiProcessorCount
//      (runtime truth, handles partitioning; capture-safe queries, cached).
//   2) hipLaunchCooperativeKernel (harness-supported) guarantees residency;
//      falls back to plain launch if it errors (custom barrier works either way).
//   3) bounded barrier spin (~20ms/barrier): worst case -> wrong answer + counters,
//      never a dead container.

typedef __attribute__((ext_vector_type(8))) short bf16x8;
typedef __attribute__((ext_vector_type(4))) float f32x4;

#define NPB 128            // nodes per bucket (bucket = dst >> 7)
#define BCAP 2560          // per-bucket staging capacity
#define EPB 4096           // edges per distribute vblock (16KB LDS stage)
#define EPT 16             // edges per thread (256 thr)
#define CPAD 16            // global counter stride in ints

__device__ __forceinline__ unsigned short f2bf(float f) {
    unsigned int u = __builtin_bit_cast(unsigned int, f);
    u += 0x7fffu + ((u >> 16) & 1u);           // round-to-nearest-even
    return (unsigned short)(u >> 16);
}
__device__ __forceinline__ float bf2f(unsigned int bits16) {
    return __builtin_bit_cast(float, bits16 << 16);
}

// ---------------- software grid barrier (bounded spin = hang-proof) ----------------

__device__ __forceinline__ void grid_barrier(unsigned* cnt, unsigned* gen, unsigned nb) {
    __syncthreads();
    if (threadIdx.x == 0) {
        __threadfence();                         // release our phase's stores
        unsigned g = __hip_atomic_load(gen, __ATOMIC_RELAXED, __HIP_MEMORY_SCOPE_AGENT);
        unsigned old = __hip_atomic_fetch_add(cnt, 1u, __ATOMIC_ACQ_REL,
                                              __HIP_MEMORY_SCOPE_AGENT);
        if (old == nb - 1u) {
            __hip_atomic_store(cnt, 0u, __ATOMIC_RELAXED, __HIP_MEMORY_SCOPE_AGENT);
            __hip_atomic_fetch_add(gen, 1u, __ATOMIC_ACQ_REL, __HIP_MEMORY_SCOPE_AGENT);
        } else {
            int spin = 0;
            while (__hip_atomic_load(gen, __ATOMIC_ACQUIRE, __HIP_MEMORY_SCOPE_AGENT) == g) {
                __builtin_amdgcn_s_sleep(8);
                if (++spin > 100000) break;      // ~20ms cap: degrade, don't hang
            }
        }
        __threadfence();                         // acquire other blocks' stores
    }
    __syncthreads();
}

// ---------------- GEMM body (R12, smem-arena version + trailing sync) ----------------

template<int GY>
__device__ __forceinline__ void gemm_body(unsigned char* smem, int mb, int y,
                                          const unsigned short* __restrict__ H,
                                          const unsigned short* __restrict__ Wl,
                                          const unsigned short* __restrict__ Wr,
                                          unsigned short* __restrict__ Cl,
                                          unsigned short* __restrict__ Cr, int N) {
    unsigned short* clds = (unsigned short*)smem;  // 4*32*68*2 = 17408 B
    const int halfY = GY >> 1;
    const int ldc = GY * 32;
    int wave = threadIdx.x >> 6;
    int lane = threadIdx.x & 63;
    int l15 = lane & 15, quad = lane >> 4;
    bool isL = y < halfY;
    const unsigned short* W = isL ? Wl : Wr;
    unsigned short* Cp = isL ? Cl : Cr;
    int yy = isL ? y : y - halfY;
    int wrow0 = yy * 64;
    int col0 = yy * 64;
    int m0 = mb * 128 + wave * 32;

    int r0 = m0 + l15;      if (r0 > N - 1) r0 = N - 1;
    int r1 = m0 + 16 + l15; if (r1 > N - 1) r1 = N - 1;
    const bf16x8* A0 = (const bf16x8*)(H + (size_t)r0 * 128);
    const bf16x8* A1 = (const bf16x8*)(H + (size_t)r1 * 128);

    f32x4 acc[2][4] = {};
#pragma unroll
    for (int ks = 0; ks < 4; ++ks) {
        int vidx = ks * 4 + quad;
        bf16x8 a0 = A0[vidx];
        bf16x8 a1 = A1[vidx];
#pragma unroll
        for (int j = 0; j < 4; ++j) {
            const bf16x8* B = (const bf16x8*)(W + (size_t)(wrow0 + j * 16 + l15) * 128);
            bf16x8 b = B[vidx];
            acc[0][j] = __builtin_amdgcn_mfma_f32_16x16x32_bf16(a0, b, acc[0][j], 0, 0, 0);
            acc[1][j] = __builtin_amdgcn_mfma_f32_16x16x32_bf16(a1, b, acc[1][j], 0, 0, 0);
        }
    }

    unsigned short* slice = clds + wave * (32 * 68);
#pragma unroll
    for (int i = 0; i < 2; ++i)
#pragma unroll
        for (int j = 0; j < 4; ++j)
#pragma unroll
            for (int r = 0; r < 4; ++r)
                slice[(i * 16 + quad * 4 + r) * 68 + j * 16 + l15] = f2bf(acc[i][j][r]);
    __syncthreads();

    int rlo = lane >> 3, j8 = lane & 7;
#pragma unroll
    for (int pass = 0; pass < 4; ++pass) {
        int row_local = pass * 8 + rlo;
        const unsigned short* p = slice + row_local * 68 + j8 * 8;
        unsigned long long lo = *(const unsigned long long*)(p);
        unsigned long long hi = *(const unsigned long long*)(p + 4);
        int row = m0 + row_local;
        if (row < N) {
            unsigned long long* q = (unsigned long long*)(Cp + (size_t)row * ldc + col0 + j8 * 8);
            q[0] = lo;
            q[1] = hi;
        }
    }
    __syncthreads();                             // smem reused next iteration
}

// ---------------- agg pair body (R12 verbatim, per-wave) ----------------

__device__ __forceinline__ void agg_pair(int pr, int lane,
                                         const unsigned short* __restrict__ Cl,
                                         const unsigned short* __restrict__ Cr,
                                         const int* __restrict__ row_ptr,
                                         const int* __restrict__ adj,
                                         const float* __restrict__ bias,
                                         unsigned short* __restrict__ hout, int N) {
    int nodeA = pr * 2;
    if (nodeA >= N) return;
    int nodeB = nodeA + 1;
    bool hasB = nodeB < N;
    int g = lane >> 4, c = lane & 15;
    int begA = row_ptr[nodeA], endA = row_ptr[nodeA + 1];
    int begB = hasB ? row_ptr[nodeB] : 0;
    int endB = hasB ? row_ptr[nodeB + 1] : 0;
    float pA[8] = {}, pB[8] = {};

    int cntA = endA - begA; if (cntA > 64) cntA = 64;
    int cntB = endB - begB; if (cntB > 64) cntB = 64;
    int idxA = (cntA > 0) ? adj[begA + (lane < cntA ? lane : cntA - 1)] : 0;
    int idxB = (cntB > 0) ? adj[begB + (lane < cntB ? lane : cntB - 1)] : 0;
    int c1A = cntA - 1, c1B = cntB - 1;
    int mx = cntA > cntB ? cntA : cntB;
    for (int i = 0; i < mx; i += 16) {
        bool doA = i < cntA, doB = i < cntB;
        bf16x8 vA[4], vB[4];
        float mA[4], mB[4];
        if (doA) {
#pragma unroll
            for (int s = 0; s < 4; ++s) {
                int tt = i + s * 4 + g;
                int src = __shfl(idxA, tt > c1A ? c1A : tt);
                mA[s] = tt < cntA ? 1.f : 0.f;
                vA[s] = ((const bf16x8*)(Cl + (size_t)src * 128))[c];
            }
        }
        if (doB) {
#pragma unroll
            for (int s = 0; s < 4; ++s) {
                int tt = i + s * 4 + g;
                int src = __shfl(idxB, tt > c1B ? c1B : tt);
                mB[s] = tt < cntB ? 1.f : 0.f;
                vB[s] = ((const bf16x8*)(Cl + (size_t)src * 128))[c];
            }
        }
        if (doA) {
#pragma unroll
            for (int s = 0; s < 4; ++s)
#pragma unroll
                for (int k = 0; k < 8; ++k)
                    pA[k] += mA[s] * bf2f((unsigned short)vA[s][k]);
        }
        if (doB) {
#pragma unroll
            for (int s = 0; s < 4; ++s)
#pragma unroll
                for (int k = 0; k < 8; ++k)
                    pB[k] += mB[s] * bf2f((unsigned short)vB[s][k]);
        }
    }
    for (int e = begA + 64; e < endA; e += 64) {
        int cnt = endA - e; if (cnt > 64) cnt = 64;
        int idx = adj[e + (lane < cnt ? lane : cnt - 1)];
        int c1 = cnt - 1;
        for (int i = 0; i < cnt; i += 16) {
#pragma unroll
            for (int s = 0; s < 4; ++s) {
                int tt = i + s * 4 + g;
                int src = __shfl(idx, tt > c1 ? c1 : tt);
                float m = tt < cnt ? 1.f : 0.f;
                bf16x8 v = ((const bf16x8*)(Cl + (size_t)src * 128))[c];
#pragma unroll
                for (int k = 0; k < 8; ++k)
                    pA[k] += m * bf2f((unsigned short)v[k]);
            }
        }
    }
    for (int e = begB + 64; e < endB; e += 64) {
        int cnt = endB - e; if (cnt > 64) cnt = 64;
        int idx = adj[e + (lane < cnt ? lane : cnt - 1)];
        int c1 = cnt - 1;
        for (int i = 0; i < cnt; i += 16) {
#pragma unroll
            for (int s = 0; s < 4; ++s) {
                int tt = i + s * 4 + g;
                int src = __shfl(idx, tt > c1 ? c1 : tt);
                float m = tt < cnt ? 1.f : 0.f;
                bf16x8 v = ((const bf16x8*)(Cl + (size_t)src * 128))[c];
#pragma unroll
                for (int k = 0; k < 8; ++k)
                    pB[k] += m * bf2f((unsigned short)v[k]);
            }
        }
    }

#pragma unroll
    for (int k = 0; k < 8; ++k) {
        pA[k] += __shfl_xor(pA[k], 16);
        pA[k] += __shfl_xor(pA[k], 32);
        pB[k] += __shfl_xor(pB[k], 16);
        pB[k] += __shfl_xor(pB[k], 32);
    }

    int degA = endA - begA, degB = endB - begB;
    float invA = 1.0f / (float)(degA > 1 ? degA : 1);
    float invB = 1.0f / (float)(degB > 1 ? degB : 1);
    bf16x8 svA = ((const bf16x8*)(Cr + (size_t)nodeA * 128))[c];
    bf16x8 svB = hasB ? ((const bf16x8*)(Cr + (size_t)nodeB * 128))[c] : svA;
    float4 b0 = ((const float4*)bias)[2 * c];
    float4 b1 = ((const float4*)bias)[2 * c + 1];
    float bb[8] = {b0.x, b0.y, b0.z, b0.w, b1.x, b1.y, b1.z, b1.w};
    bf16x8 oA, oB;
#pragma unroll
    for (int k = 0; k < 8; ++k) {
        oA[k] = (short)f2bf(fmaxf(pA[k] * invA + bb[k] + bf2f((unsigned short)svA[k]), 0.f));
        oB[k] = (short)f2bf(fmaxf(pB[k] * invB + bb[k] + bf2f((unsigned short)svB[k]), 0.f));
    }
    if (g == 0)
        ((bf16x8*)(hout + (size_t)nodeA * 128))[c] = oA;
    else if (g == 1 && hasB)
        ((bf16x8*)(hout + (size_t)nodeB * 128))[c] = oB;
}

// ---------------- final pair body (R12 verbatim, per-wave) ----------------

__device__ __forceinline__ void final_pair(int pr, int lane,
                                           const unsigned short* __restrict__ Cl2,
                                           const unsigned short* __restrict__ Cr2,
                                           const int* __restrict__ row_ptr,
                                           const int* __restrict__ adj,
                                           const float* __restrict__ bias,
                                           float* __restrict__ out, int N) {
    int nodeA = pr * 2;
    if (nodeA >= N) return;
    int nodeB = nodeA + 1;
    bool hasB = nodeB < N;
    int g = lane >> 3, c = lane & 7;
    int begA = row_ptr[nodeA], endA = row_ptr[nodeA + 1];
    int begB = hasB ? row_ptr[nodeB] : 0;
    int endB = hasB ? row_ptr[nodeB + 1] : 0;
    float pA[8] = {}, pB[8] = {};

    int cntA = endA - begA; if (cntA > 64) cntA = 64;
    int cntB = endB - begB; if (cntB > 64) cntB = 64;
    int idxA = (cntA > 0) ? adj[begA + (lane < cntA ? lane : cntA - 1)] : 0;
    int idxB = (cntB > 0) ? adj[begB + (lane < cntB ? lane : cntB - 1)] : 0;
    int c1A = cntA - 1, c1B = cntB - 1;
    int mx = cntA > cntB ? cntA : cntB;
    for (int i = 0; i < mx; i += 16) {
        bool doA = i < cntA, doB = i < cntB;
        bf16x8 vA[2], vB[2];
        float mA[2], mB[2];
        if (doA) {
#pragma unroll
            for (int s = 0; s < 2; ++s) {
                int tt = i + s * 8 + g;
                int src = __shfl(idxA, tt > c1A ? c1A : tt);
                mA[s] = tt < cntA ? 1.f : 0.f;
                vA[s] = ((const bf16x8*)(Cl2 + (size_t)src * 64))[c];
            }
        }
        if (doB) {
#pragma unroll
            for (int s = 0; s < 2; ++s) {
                int tt = i + s * 8 + g;
                int src = __shfl(idxB, tt > c1B ? c1B : tt);
                mB[s] = tt < cntB ? 1.f : 0.f;
                vB[s] = ((const bf16x8*)(Cl2 + (size_t)src * 64))[c];
            }
        }
        if (doA) {
#pragma unroll
            for (int s = 0; s < 2; ++s)
#pragma unroll
                for (int k = 0; k < 8; ++k)
                    pA[k] += mA[s] * bf2f((unsigned short)vA[s][k]);
        }
        if (doB) {
#pragma unroll
            for (int s = 0; s < 2; ++s)
#pragma unroll
                for (int k = 0; k < 8; ++k)
                    pB[k] += mB[s] * bf2f((unsigned short)vB[s][k]);
        }
    }
    for (int e = begA + 64; e < endA; e += 64) {
        int cnt = endA - e; if (cnt > 64) cnt = 64;
        int idx = adj[e + (lane < cnt ? lane : cnt - 1)];
        int c1 = cnt - 1;
        for (int i = 0; i < cnt; i += 16) {
#pragma unroll
            for (int s = 0; s < 2; ++s) {
                int tt = i + s * 8 + g;
                int src = __shfl(idx, tt > c1 ? c1 : tt);
                float m = tt < cnt ? 1.f : 0.f;
                bf16x8 v = ((const bf16x8*)(Cl2 + (size_t)src * 64))[c];
#pragma unroll
                for (int k = 0; k < 8; ++k)
                    pA[k] += m * bf2f((unsigned short)v[k]);
            }
        }
    }
    for (int e = begB + 64; e < endB; e += 64) {
        int cnt = endB - e; if (cnt > 64) cnt = 64;
        int idx = adj[e + (lane < cnt ? lane : cnt - 1)];
        int c1 = cnt - 1;
        for (int i = 0; i < cnt; i += 16) {
#pragma unroll
            for (int s = 0; s < 2; ++s) {
                int tt = i + s * 8 + g;
                int src = __shfl(idx, tt > c1 ? c1 : tt);
                float m = tt < cnt ? 1.f : 0.f;
                bf16x8 v = ((const bf16x8*)(Cl2 + (size_t)src * 64))[c];
#pragma unroll
                for (int k = 0; k < 8; ++k)
                    pB[k] += m * bf2f((unsigned short)v[k]);
            }
        }
    }

#pragma unroll
    for (int k = 0; k < 8; ++k) {
        pA[k] += __shfl_xor(pA[k], 8);
        pA[k] += __shfl_xor(pA[k], 16);
        pA[k] += __shfl_xor(pA[k], 32);
        pB[k] += __shfl_xor(pB[k], 8);
        pB[k] += __shfl_xor(pB[k], 16);
        pB[k] += __shfl_xor(pB[k], 32);
    }

    int degA = endA - begA, degB = endB - begB;
    float invA = 1.0f / (float)(degA > 1 ? degA : 1);
    float invB = 1.0f / (float)(degB > 1 ? degB : 1);
    bf16x8 svA = ((const bf16x8*)(Cr2 + (size_t)nodeA * 64))[c];
    bf16x8 svB = hasB ? ((const bf16x8*)(Cr2 + (size_t)nodeB * 64))[c] : svA;
    float4 b0 = ((const float4*)bias)[2 * c];
    float4 b1 = ((const float4*)bias)[2 * c + 1];
    float bb[8] = {b0.x, b0.y, b0.z, b0.w, b1.x, b1.y, b1.z, b1.w};
    float uA[8], uB[8];
#pragma unroll
    for (int k = 0; k < 8; ++k) {
        uA[k] = pA[k] * invA + bb[k] + bf2f((unsigned short)svA[k]);
        uB[k] = pB[k] * invB + bb[k] + bf2f((unsigned short)svB[k]);
    }

    float mA_ = uA[0], mB_ = uB[0];
#pragma unroll
    for (int k = 1; k < 8; ++k) { mA_ = fmaxf(mA_, uA[k]); mB_ = fmaxf(mB_, uB[k]); }
#pragma unroll
    for (int off = 1; off < 8; off <<= 1) {
        mA_ = fmaxf(mA_, __shfl_xor(mA_, off));
        mB_ = fmaxf(mB_, __shfl_xor(mB_, off));
    }
    float seA = 0.f, seB = 0.f;
#pragma unroll
    for (int k = 0; k < 8; ++k) { seA += __expf(uA[k] - mA_); seB += __expf(uB[k] - mB_); }
#pragma unroll
    for (int off = 1; off < 8; off <<= 1) {
        seA += __shfl_xor(seA, off);
        seB += __shfl_xor(seB, off);
    }
    float lsA = __logf(seA), lsB = __logf(seB);

    if (g == 0) {
        float4 o0 = {uA[0] - mA_ - lsA, uA[1] - mA_ - lsA, uA[2] - mA_ - lsA, uA[3] - mA_ - lsA};
        float4 o1 = {uA[4] - mA_ - lsA, uA[5] - mA_ - lsA, uA[6] - mA_ - lsA, uA[7] - mA_ - lsA};
        ((float4*)(out + (size_t)nodeA * 64))[2 * c] = o0;
        ((float4*)(out + (size_t)nodeA * 64))[2 * c + 1] = o1;
    } else if (g == 1 && hasB) {
        float4 o0 = {uB[0] - mB_ - lsB, uB[1] - mB_ - lsB, uB[2] - mB_ - lsB, uB[3] - mB_ - lsB};
        float4 o1 = {uB[4] - mB_ - lsB, uB[5] - mB_ - lsB, uB[6] - mB_ - lsB, uB[7] - mB_ - lsB};
        ((float4*)(out + (size_t)nodeB * 64))[2 * c] = o0;
        ((float4*)(out + (size_t)nodeB * 64))[2 * c + 1] = o1;
    }
}

// ---------------- the persistent mega-kernel ----------------

__global__ __launch_bounds__(256, 4) void mega_kernel(
        const int* __restrict__ dstp, const int* __restrict__ srcp,
        int* __restrict__ gcnt, unsigned* __restrict__ bar,
        unsigned int* __restrict__ staging,
        int E, int N, int NBc, int DB, int XB, int gemmRows, int pairVB,
        const float* __restrict__ x, unsigned short* __restrict__ xbf,
        const float* __restrict__ w0, const float* __restrict__ w1,
        const float* __restrict__ w2, const float* __restrict__ w3,
        const float* __restrict__ w4, const float* __restrict__ w5,
        unsigned short* __restrict__ wbf,
        int* __restrict__ row_ptr, int* __restrict__ adj,
        const float* __restrict__ bl0, const float* __restrict__ bl1,
        const float* __restrict__ bl2,
        unsigned short* __restrict__ Cl, unsigned short* __restrict__ Cr,
        unsigned short* __restrict__ hA, unsigned short* __restrict__ hB,
        float* __restrict__ out) {
    __shared__ __align__(16) unsigned char smem[22208];
    int t = threadIdx.x;
    unsigned* bcnt = bar;
    unsigned* bgen = bar + 16;                   // 64B apart from cnt
    unsigned nb = gridDim.x;

    const unsigned short* wl0 = wbf;
    const unsigned short* wr0 = wbf + 16384;
    const unsigned short* wl1 = wbf + 32768;
    const unsigned short* wr1 = wbf + 49152;
    const unsigned short* wl2 = wbf + 65536;
    const unsigned short* wr2 = wbf + 73728;

    // ---------------- P1: distribute + x-cast + w-cast ----------------
    int P1 = DB + XB + 160;
    for (int vb = blockIdx.x; vb < P1; vb += gridDim.x) {
        if (vb < DB) {
            unsigned int* stage = (unsigned int*)smem;            // 16384 B
            int* hist   = (int*)(smem + 16384);                   // 400
            int* lstart = (int*)(smem + 16384 + 1600);            // 400
            int* gbase  = (int*)(smem + 16384 + 3200);            // 400
            int* scanbuf= (int*)(smem + 16384 + 4800);            // 256
            int e0 = vb * EPB;
            unsigned int w[EPT];

            for (int b = t; b < NBc + 1; b += 256) hist[b] = 0;
            __syncthreads();
#pragma unroll
            for (int i = 0; i < EPT; ++i) {
                int e = e0 + i * 256 + t;
                unsigned int word = 0xFFFFFFFFu;
                if (e < E) word = ((unsigned int)dstp[e] << 16) | (unsigned int)srcp[e];
                w[i] = word;
                int b = (int)(word >> 23); if (b > NBc) b = NBc;
                atomicAdd(&hist[b], 1);
            }
            __syncthreads();

            int b0 = 2 * t, b1 = 2 * t + 1;
            int h0 = (b0 <= NBc) ? hist[b0] : 0;
            int h1 = (b1 <= NBc) ? hist[b1] : 0;
            int pair = h0 + h1;
            scanbuf[t] = pair;
            __syncthreads();
            for (int off = 1; off < 256; off <<= 1) {
                int v = (t >= off) ? scanbuf[t - off] : 0;
                __syncthreads();
                scanbuf[t] += v;
                __syncthreads();
            }
            int excl = scanbuf[t] - pair;
            if (b0 <= NBc) lstart[b0] = excl;
            if (b1 <= NBc) lstart[b1] = excl + h0;
            __syncthreads();

            for (int b = t; b < NBc; b += 256) {
                int h = hist[b];
                gbase[b] = h ? atomicAdd(&gcnt[b * CPAD], h) : 0;
            }
            for (int b = t; b < NBc + 1; b += 256) hist[b] = lstart[b];
            __syncthreads();

#pragma unroll
            for (int i = 0; i < EPT; ++i) {
                unsigned int word = w[i];
                int b = (int)(word >> 23); if (b > NBc) b = NBc;
                int p = atomicAdd(&hist[b], 1);
                stage[p] = word;
            }
            __syncthreads();

            int total = lstart[NBc];
            for (int i = t; i < total; i += 256) {
                unsigned int word = stage[i];
                int b = (int)(word >> 23);
                int gpos = gbase[b] + (i - lstart[b]);
                staging[(size_t)b * BCAP + gpos] = word;
            }
            __syncthreads();                     // smem reused next iteration
        } else if (vb < DB + XB) {
            int base = (vb - DB) * 256 + t;
            int stride = XB * 256;
            const float2* x2 = (const float2*)x;
            unsigned int* xo = (unsigned int*)xbf;
#pragma unroll
            for (int k = 0; k < 4; ++k) {
                int idx = base + k * stride;
                float2 v = x2[idx];
                xo[idx] = (unsigned int)f2bf(v.x) | ((unsigned int)f2bf(v.y) << 16);
            }
        } else {
            int w = (vb - DB - XB) * 256 + t;
            if (w < 40960) {
                const float* src;
                int local;
                if      (w < 8192)  { src = w0; local = w; }
                else if (w < 16384) { src = w1; local = w - 8192; }
                else if (w < 24576) { src = w2; local = w - 16384; }
                else if (w < 32768) { src = w3; local = w - 24576; }
                else if (w < 36864) { src = w4; local = w - 32768; }
                else                { src = w5; local = w - 36864; }
                float2 v = ((const float2*)src)[local];
                unsigned int p = (unsigned int)f2bf(v.x) | ((unsigned int)f2bf(v.y) << 16);
                ((unsigned int*)wbf)[w] = p;
            }
        }
    }
    grid_barrier(bcnt, bgen, nb);

    // ---------------- P2: build + GEMM0 ----------------
    int P2 = NBc + gemmRows * 4;
    for (int vb = blockIdx.x; vb < P2; vb += gridDim.x) {
        if (vb >= NBc) {
            int gid = vb - NBc;
            gemm_body<4>(smem, gid % gemmRows, gid / gemmRows, xbf, wl0, wr0, Cl, Cr, N);
            continue;
        }
        int* hist = (int*)smem;                  // 128
        int* scn  = (int*)(smem + 512);          // 128
        int* wsum = (int*)(smem + 1024);         // 4
        int b = vb;
        int n0 = b * NPB;
        int nbn = N - n0; if (nbn > NPB) nbn = NPB;
        int ec = gcnt[b * CPAD];
        const unsigned int* st = staging + (size_t)b * BCAP;

        int a = 0;
        for (int j = t; j < b; j += 256) a += gcnt[j * CPAD];
#pragma unroll
        for (int off = 32; off; off >>= 1) a += __shfl_xor(a, off);
        if ((t & 63) == 0) wsum[t >> 6] = a;
        if (t < NPB) hist[t] = 0;
        __syncthreads();
        int bb = wsum[0] + wsum[1] + wsum[2] + wsum[3];

        for (int i = t; i < ec; i += 256)
            atomicAdd(&hist[(st[i] >> 16) & (NPB - 1)], 1);
        __syncthreads();

        int v = (t < NPB) ? hist[t] : 0;
        if (t < NPB) scn[t] = v;
        __syncthreads();
        for (int off = 1; off < NPB; off <<= 1) {
            int u = (t >= off && t < NPB) ? scn[t - off] : 0;
            __syncthreads();
            if (t < NPB) scn[t] += u;
            __syncthreads();
        }
        if (t < NPB) hist[t] = scn[t] - v;
        if (t < nbn) row_ptr[n0 + t] = bb + (scn[t] - v);
        if (b == NBc - 1 && t == 0) row_ptr[N] = bb + ec;
        __syncthreads();

        for (int i = t; i < ec; i += 256) {
            unsigned int pk = st[i];
            int p = atomicAdd(&hist[(pk >> 16) & (NPB - 1)], 1);
            adj[bb + p] = (int)(pk & 0xffffu);
        }
        __syncthreads();                         // smem reused next iteration
    }
    grid_barrier(bcnt, bgen, nb);

    // ---------------- P3: agg0 ----------------
    for (int vb = blockIdx.x; vb < pairVB; vb += gridDim.x)
        agg_pair(vb * 4 + (t >> 6), t & 63, Cl, Cr, row_ptr, adj, bl0, hA, N);
    grid_barrier(bcnt, bgen, nb);

    // ---------------- P4: GEMM1 ----------------
    for (int vb = blockIdx.x; vb < gemmRows * 4; vb += gridDim.x)
        gemm_body<4>(smem, vb % gemmRows, vb / gemmRows, hA, wl1, wr1, Cl, Cr, N);
    grid_barrier(bcnt, bgen, nb);

    // ---------------- P5: agg1 ----------------
    for (int vb = blockIdx.x; vb < pairVB; vb += gridDim.x)
        agg_pair(vb * 4 + (t >> 6), t & 63, Cl, Cr, row_ptr, adj, bl1, hB, N);
    grid_barrier(bcnt, bgen, nb);

    // ---------------- P6: GEMM2 ----------------
    for (int vb = blockIdx.x; vb < gemmRows * 2; vb += gridDim.x)
        gemm_body<2>(smem, vb % gemmRows, vb / gemmRows, hB, wl2, wr2, Cl, Cr, N);
    grid_barrier(bcnt, bgen, nb);

    // ---------------- P7: final + log_softmax ----------------
    for (int vb = blockIdx.x; vb < pairVB; vb += gridDim.x)
        final_pair(vb * 4 + (t >> 6), t & 63, Cl, Cr, row_ptr, adj, bl2, out, N);
}

// ---------------- Launch ----------------

extern "C" void kernel_launch(void* const* d_in, const int* in_sizes, int n_in,
                              void* d_out, int out_size, void* d_ws, size_t ws_size,
                              hipStream_t stream) {
    const float* x   = (const float*)d_in[0];
    const int*   ei  = (const int*)d_in[1];
    const float* Wl0 = (const float*)d_in[2];
    const float* bl0 = (const float*)d_in[3];
    const float* Wr0 = (const float*)d_in[4];
    const float* Wl1 = (const float*)d_in[5];
    const float* bl1 = (const float*)d_in[6];
    const float* Wr1 = (const float*)d_in[7];
    const float* Wl2 = (const float*)d_in[8];
    const float* bl2 = (const float*)d_in[9];
    const float* Wr2 = (const float*)d_in[10];
    float* out = (float*)d_out;

    const int N  = in_sizes[0] / 128;   // 50000
    const int E  = in_sizes[1] / 2;     // 800000
    const int NB = (N + NPB - 1) / NPB; // 391 buckets

    char* ws = (char*)d_ws;
    auto alloc = [&](size_t bytes) {
        char* p = ws;
        ws += (bytes + 255) & ~(size_t)255;
        return p;
    };
    int*   row_ptr    = (int*)alloc((size_t)(N + 1) * 4);
    int*   adj        = (int*)alloc((size_t)E * 4);
    int*   gcnt       = (int*)alloc((size_t)NB * CPAD * 4 + 128);  // + barrier vars
    unsigned int* staging = (unsigned int*)alloc((size_t)NB * BCAP * 4);
    unsigned short* xbf = (unsigned short*)alloc((size_t)N * 128 * 2);
    unsigned short* wbf = (unsigned short*)alloc((size_t)81920 * 2);
    unsigned short* Cl  = (unsigned short*)alloc((size_t)N * 128 * 2);
    unsigned short* Cr  = (unsigned short*)alloc((size_t)N * 128 * 2);
    unsigned short* hA  = (unsigned short*)alloc((size_t)N * 128 * 2);
    unsigned short* hB  = (unsigned short*)alloc((size_t)N * 128 * 2);

    const int* dstp = ei;       // edge_index row 0 = dst
    const int* srcp = ei + E;   // edge_index row 1 = src
    unsigned* bar = (unsigned*)(gcnt + NB * CPAD);

    int DB = (E + EPB - 1) / EPB;       // 196 distribute vblocks
    int XB = (N * 64) / (256 * 4);      // 3125 x-cast vblocks
    int gemmRows = (N + 127) / 128;     // 391
    int pairVB = ((N + 1) / 2 + 3) / 4; // 6250

    // runtime-derived co-resident grid (capture-safe queries, cached)
    static int gridBlocks = 0;
    if (gridBlocks == 0) {
        int dev = 0;
        hipGetDevice(&dev);
        int numCU = 0;
        hipDeviceGetAttribute(&numCU, hipDeviceAttributeMultiprocessorCount, dev);
        if (numCU < 1) numCU = 256;
        int occ = 0;
        hipOccupancyMaxActiveBlocksPerMultiprocessor(&occ, mega_kernel, 256, 0);
        if (occ < 1) occ = 1;
        gridBlocks = occ * numCU;
        if (gridBlocks > 2048) gridBlocks = 2048;
    }

    // zero bucket counters + barrier state
    hipMemsetAsync(gcnt, 0, (size_t)NB * CPAD * 4 + 128, stream);

    int E_ = E, N_ = N, NB_ = NB;
    void* args[] = { &dstp, &srcp, &gcnt, &bar, &staging,
                     &E_, &N_, &NB_, &DB, &XB, &gemmRows, &pairVB,
                     &x, &xbf,
                     &Wl0, &Wr0, &Wl1, &Wr1, &Wl2, &Wr2, &wbf,
                     &row_ptr, &adj, &bl0, &bl1, &bl2,
                     &Cl, &Cr, &hA, &hB, &out };
    hipError_t err = hipLaunchCooperativeKernel(mega_kernel, dim3(gridBlocks), dim3(256),
                                                args, 0, stream);
    if (err != hipSuccess) {
        // fallback: plain launch (grid <= capacity -> co-resident in practice;
        // barrier spin is bounded either way)
        mega_kernel<<<gridBlocks, 256, 0, stream>>>(dstp, srcp, gcnt, bar, staging,
                                                    E_, N_, NB_, DB, XB, gemmRows, pairVB,
                                                    x, xbf,
                                                    Wl0, Wr0, Wl1, Wr1, Wl2, Wr2, wbf,
                                                    row_ptr, adj, bl0, bl1, bl2,
                                                    Cl, Cr, hA, hB, out);
    }
}

// Round 10
// 284.133 us; speedup vs baseline: 2.5240x; 2.5240x over previous
//
#include <hip/hip_runtime.h>
#include <hip/hip_bf16.h>

// GraphSAGE 3-layer forward, MI355X. Round 15: XCD-local column-sliced aggregation.
//  - R14 mega-kernel postmortem: VGPR=64 forced spills (+200MB scratch traffic,
//    717us); harness graph-capture means launch boundaries were already ~2-3us
//    each. Real mass: gather phases ~170us (512MB logical @ ~2.9TB/s, L2 hit
//    ~31%: random sources over a 12.8MB table vs 4MB per-XCD L2).
//  - Fix: aggregation is column-separable. Cl/hA/hB stored SLICE-MAJOR
//    [8][N][16 cols]; slice s processed by blocks with blockIdx&7==s (XCD
//    round-robin heuristic) -> each XCD re-reads only its own 1.6MB
//    L2-resident slice. Agg becomes per-lane serial fold (no shfl/LDS/masks).
//  - GEMM A-loads templated for sliced layout (same 16B loads, remapped addr);
//    GEMM epilogue writes Cl sliced (contiguous 1KB stores). Cr stays
//    row-major (self-term read is streaming). Layer-2/final unchanged
//    (row-major, R12 paired final). CSR build + fused casts unchanged (R11).

typedef __attribute__((ext_vector_type(8))) short bf16x8;
typedef __attribute__((ext_vector_type(4))) float f32x4;

#define NPB 128            // nodes per bucket (bucket = dst >> 7)
#define BCAP 2560          // per-bucket staging capacity
#define EPB 8192           // edges per distribute block
#define EPT 32             // edges per thread (256 thr)
#define CPAD 16            // global counter stride in ints

__device__ __forceinline__ unsigned short f2bf(float f) {
    unsigned int u = __builtin_bit_cast(unsigned int, f);
    u += 0x7fffu + ((u >> 16) & 1u);           // round-to-nearest-even
    return (unsigned short)(u >> 16);
}
__device__ __forceinline__ float bf2f(unsigned int bits16) {
    return __builtin_bit_cast(float, bits16 << 16);
}

// ---------------- distribute + x-cast + weight-cast (fused, block ranges) --------

__global__ __launch_bounds__(256) void dist_cast_kernel(const int* __restrict__ dst,
                                                        const int* __restrict__ srcv,
                                                        int* __restrict__ gcnt,
                                                        unsigned int* __restrict__ staging,
                                                        int E, int NBc, int DB, int XB,
                                                        const float* __restrict__ x,
                                                        unsigned short* __restrict__ xbf,
                                                        const float* p0, const float* p1,
                                                        const float* p2, const float* p3,
                                                        const float* p4, const float* p5,
                                                        unsigned short* __restrict__ wbf) {
    __shared__ unsigned int stage[EPB];      // bucket-sorted edges (32KB)
    __shared__ int hist[400];
    __shared__ int lstart[400];
    __shared__ int gbase[400];
    __shared__ int scanbuf[256];
    int bid = blockIdx.x;
    int t = threadIdx.x;

    if (bid >= DB && bid < DB + XB) {        // ---- x cast: 4 float2 per thread ----
        int base = (bid - DB) * 256 + t;
        int stride = XB * 256;
        const float2* x2 = (const float2*)x;
        unsigned int* xo = (unsigned int*)xbf;
#pragma unroll
        for (int k = 0; k < 4; ++k) {
            int idx = base + k * stride;
            float2 v = x2[idx];
            xo[idx] = (unsigned int)f2bf(v.x) | ((unsigned int)f2bf(v.y) << 16);
        }
        return;
    }
    if (bid >= DB + XB) {                    // ---- weight cast part ----
        int w = (bid - DB - XB) * 256 + t;
        if (w < 40960) {
            const float* src;
            int local;
            if      (w < 8192)  { src = p0; local = w; }
            else if (w < 16384) { src = p1; local = w - 8192; }
            else if (w < 24576) { src = p2; local = w - 16384; }
            else if (w < 32768) { src = p3; local = w - 24576; }
            else if (w < 36864) { src = p4; local = w - 32768; }
            else                { src = p5; local = w - 36864; }
            float2 v = ((const float2*)src)[local];
            unsigned int p = (unsigned int)f2bf(v.x) | ((unsigned int)f2bf(v.y) << 16);
            ((unsigned int*)wbf)[w] = p;
        }
        return;
    }

    // ---- distribute part ----
    int e0 = bid * EPB;
    unsigned int w[EPT];

    for (int b = t; b < NBc + 1; b += 256) hist[b] = 0;
    __syncthreads();

#pragma unroll
    for (int i = 0; i < EPT; ++i) {
        int e = e0 + i * 256 + t;
        unsigned int word = 0xFFFFFFFFu;
        if (e < E) word = ((unsigned int)dst[e] << 16) | (unsigned int)srcv[e];
        w[i] = word;
        int b = (int)(word >> 23); if (b > NBc) b = NBc;
        atomicAdd(&hist[b], 1);
    }
    __syncthreads();

    int b0 = 2 * t, b1 = 2 * t + 1;
    int h0 = (b0 <= NBc) ? hist[b0] : 0;
    int h1 = (b1 <= NBc) ? hist[b1] : 0;
    int pair = h0 + h1;
    scanbuf[t] = pair;
    __syncthreads();
    for (int off = 1; off < 256; off <<= 1) {
        int v = (t >= off) ? scanbuf[t - off] : 0;
        __syncthreads();
        scanbuf[t] += v;
        __syncthreads();
    }
    int excl = scanbuf[t] - pair;
    if (b0 <= NBc) lstart[b0] = excl;
    if (b1 <= NBc) lstart[b1] = excl + h0;
    __syncthreads();

    for (int b = t; b < NBc; b += 256) {
        int h = hist[b];
        gbase[b] = h ? atomicAdd(&gcnt[b * CPAD], h) : 0;
    }
    for (int b = t; b < NBc + 1; b += 256) hist[b] = lstart[b];
    __syncthreads();

#pragma unroll
    for (int i = 0; i < EPT; ++i) {
        unsigned int word = w[i];
        int b = (int)(word >> 23); if (b > NBc) b = NBc;
        int p = atomicAdd(&hist[b], 1);
        stage[p] = word;
    }
    __syncthreads();

    int total = lstart[NBc];
    for (int i = t; i < total; i += 256) {
        unsigned int word = stage[i];
        int b = (int)(word >> 23);
        int gpos = gbase[b] + (i - lstart[b]);
        staging[(size_t)b * BCAP + gpos] = word;
    }
}

// ---------------- GEMM body: light geometry, templated layouts ----------------
// Block = 128 rows x 64 cols (col-group y of GY). y < GY/2 -> Wl, else Wr.
// ASL: A stored slice-major [8][N][16]. CSL: Cl output slice-major; Cr always
// row-major (ldc = GY*32). LDS-staged epilogue either way.

template<int GY, int ASL, int CSL>
__device__ __forceinline__ void gemm_body(int mb, int y,
                                          const unsigned short* __restrict__ H,
                                          const unsigned short* __restrict__ Wl,
                                          const unsigned short* __restrict__ Wr,
                                          unsigned short* __restrict__ Cl,
                                          unsigned short* __restrict__ Cr, int N) {
    __shared__ unsigned short clds[4 * 32 * 68];   // 17408 B
    const int halfY = GY >> 1;
    const int ldc = GY * 32;
    int wave = threadIdx.x >> 6;
    int lane = threadIdx.x & 63;
    int l15 = lane & 15, quad = lane >> 4;
    bool isL = y < halfY;
    const unsigned short* W = isL ? Wl : Wr;
    unsigned short* Cp = isL ? Cl : Cr;
    int yy = isL ? y : y - halfY;
    int wrow0 = yy * 64;
    int col0 = yy * 64;
    int m0 = mb * 128 + wave * 32;

    int r0 = m0 + l15;      if (r0 > N - 1) r0 = N - 1;
    int r1 = m0 + 16 + l15; if (r1 > N - 1) r1 = N - 1;

    f32x4 acc[2][4] = {};
#pragma unroll
    for (int ks = 0; ks < 4; ++ks) {
        int vidx = ks * 4 + quad;
        bf16x8 a0, a1;
        if constexpr (ASL) {
            const unsigned short* base = H + (size_t)(vidx >> 1) * N * 16 + (vidx & 1) * 8;
            a0 = *(const bf16x8*)(base + (size_t)r0 * 16);
            a1 = *(const bf16x8*)(base + (size_t)r1 * 16);
        } else {
            a0 = ((const bf16x8*)(H + (size_t)r0 * 128))[vidx];
            a1 = ((const bf16x8*)(H + (size_t)r1 * 128))[vidx];
        }
#pragma unroll
        for (int j = 0; j < 4; ++j) {
            const bf16x8* B = (const bf16x8*)(W + (size_t)(wrow0 + j * 16 + l15) * 128);
            bf16x8 b = B[vidx];
            acc[0][j] = __builtin_amdgcn_mfma_f32_16x16x32_bf16(a0, b, acc[0][j], 0, 0, 0);
            acc[1][j] = __builtin_amdgcn_mfma_f32_16x16x32_bf16(a1, b, acc[1][j], 0, 0, 0);
        }
    }

    unsigned short* slice = clds + wave * (32 * 68);
#pragma unroll
    for (int i = 0; i < 2; ++i)
#pragma unroll
        for (int j = 0; j < 4; ++j)
#pragma unroll
            for (int r = 0; r < 4; ++r)
                slice[(i * 16 + quad * 4 + r) * 68 + j * 16 + l15] = f2bf(acc[i][j][r]);
    __syncthreads();

    if (CSL && isL) {
        // slice-major Cl: slices col0/16 .. +3, contiguous [node][16] chunks
        int nodeLocal = lane >> 1, hf = lane & 1;
        int row = m0 + nodeLocal;
        int s0 = col0 >> 4;
        if (row < N) {
#pragma unroll
            for (int sl = 0; sl < 4; ++sl) {
                const unsigned short* p = slice + nodeLocal * 68 + sl * 16 + hf * 8;
                unsigned long long lo = *(const unsigned long long*)(p);
                unsigned long long hi = *(const unsigned long long*)(p + 4);
                unsigned long long* q =
                    (unsigned long long*)(Cl + ((size_t)(s0 + sl) * N + row) * 16 + hf * 8);
                q[0] = lo;
                q[1] = hi;
            }
        }
    } else {
        int rlo = lane >> 3, j8 = lane & 7;
#pragma unroll
        for (int pass = 0; pass < 4; ++pass) {
            int row_local = pass * 8 + rlo;
            const unsigned short* p = slice + row_local * 68 + j8 * 8;
            unsigned long long lo = *(const unsigned long long*)(p);
            unsigned long long hi = *(const unsigned long long*)(p + 4);
            int row = m0 + row_local;
            if (row < N) {
                unsigned long long* q =
                    (unsigned long long*)(Cp + (size_t)row * ldc + col0 + j8 * 8);
                q[0] = lo;
                q[1] = hi;
            }
        }
    }
    __syncthreads();
}

// ---------------- build + GEMM0 (fused, block-range split) ----------------

__global__ __launch_bounds__(256) void build_gemm_kernel(const unsigned int* __restrict__ staging,
                                                         const int* __restrict__ gcnt,
                                                         int* __restrict__ row_ptr,
                                                         int* __restrict__ adj, int N, int NBc,
                                                         int gemmRows,
                                                         const unsigned short* __restrict__ H,
                                                         const unsigned short* __restrict__ Wl,
                                                         const unsigned short* __restrict__ Wr,
                                                         unsigned short* __restrict__ Cl,
                                                         unsigned short* __restrict__ Cr) {
    __shared__ int hist[NPB];
    __shared__ int scn[NPB];
    __shared__ int wsum[4];
    int bid = blockIdx.x;
    int t = threadIdx.x;

    if (bid >= NBc) {                        // ---- GEMM0: xbf row-major -> Cl sliced ----
        int gid = bid - NBc;
        gemm_body<4, 0, 1>(gid % gemmRows, gid / gemmRows, H, Wl, Wr, Cl, Cr, N);
        return;
    }

    // ---- build part ----
    int b = bid;
    int n0 = b * NPB;
    int nb = N - n0; if (nb > NPB) nb = NPB;
    int ec = gcnt[b * CPAD];
    const unsigned int* st = staging + (size_t)b * BCAP;

    int a = 0;
    for (int j = t; j < b; j += 256) a += gcnt[j * CPAD];
#pragma unroll
    for (int off = 32; off; off >>= 1) a += __shfl_xor(a, off);
    if ((t & 63) == 0) wsum[t >> 6] = a;
    if (t < NPB) hist[t] = 0;
    __syncthreads();
    int bb = wsum[0] + wsum[1] + wsum[2] + wsum[3];

    for (int i = t; i < ec; i += 256)
        atomicAdd(&hist[(st[i] >> 16) & (NPB - 1)], 1);
    __syncthreads();

    int v = (t < NPB) ? hist[t] : 0;
    if (t < NPB) scn[t] = v;
    __syncthreads();
    for (int off = 1; off < NPB; off <<= 1) {
        int u = (t >= off && t < NPB) ? scn[t - off] : 0;
        __syncthreads();
        if (t < NPB) scn[t] += u;
        __syncthreads();
    }
    if (t < NPB) hist[t] = scn[t] - v;
    if (t < nb) row_ptr[n0 + t] = bb + (scn[t] - v);
    if (b == NBc - 1 && t == 0) row_ptr[N] = bb + ec;
    __syncthreads();

    for (int i = t; i < ec; i += 256) {
        unsigned int pk = st[i];
        int p = atomicAdd(&hist[(pk >> 16) & (NPB - 1)], 1);
        adj[bb + p] = (int)(pk & 0xffffu);
    }
}

// ---------------- standalone GEMM (layers 1,2) ----------------

template<int GY, int ASL, int CSL>
__global__ __launch_bounds__(256) void gemm_mfma_kernel(const unsigned short* __restrict__ H,
                                                        const unsigned short* __restrict__ Wl,
                                                        const unsigned short* __restrict__ Wr,
                                                        unsigned short* __restrict__ Cl,
                                                        unsigned short* __restrict__ Cr,
                                                        int N) {
    gemm_body<GY, ASL, CSL>(blockIdx.x, blockIdx.y, H, Wl, Wr, Cl, Cr, N);
}

// ---------------- XCD-local sliced aggregation (layers 0,1) ----------------
// slice s = blockIdx&7 (XCD round-robin heuristic): each XCD re-reads only its
// 1.6MB slice of Cl -> L2-resident. Lane = (node = base+lane>>1, half=lane&1);
// lane owns 8 cols, folds its node's edges serially in adj order (4-deep
// unrolled, 4 loads in flight). No shfl, no LDS, no masks.

__global__ __launch_bounds__(256) void agg_sliced_kernel(const unsigned short* __restrict__ Cls,
                                                         const unsigned short* __restrict__ Cr,
                                                         const int* __restrict__ row_ptr,
                                                         const int* __restrict__ adj,
                                                         const float* __restrict__ bias,
                                                         unsigned short* __restrict__ houts,
                                                         int N) {
    int s = blockIdx.x & 7;
    int nb = blockIdx.x >> 3;
    int wave = threadIdx.x >> 6;
    int lane = threadIdx.x & 63;
    int node = nb * 128 + wave * 32 + (lane >> 1);
    int half = lane & 1;
    if (node >= N) return;
    int beg = row_ptr[node], end = row_ptr[node + 1];
    const unsigned short* tab = Cls + (size_t)s * N * 16 + half * 8;

    float acc[8] = {};
    int e = beg;
    for (; e + 4 <= end; e += 4) {
        int i0 = adj[e], i1 = adj[e + 1], i2 = adj[e + 2], i3 = adj[e + 3];
        bf16x8 v0 = *(const bf16x8*)(tab + (size_t)i0 * 16);
        bf16x8 v1 = *(const bf16x8*)(tab + (size_t)i1 * 16);
        bf16x8 v2 = *(const bf16x8*)(tab + (size_t)i2 * 16);
        bf16x8 v3 = *(const bf16x8*)(tab + (size_t)i3 * 16);
#pragma unroll
        for (int k = 0; k < 8; ++k) acc[k] += bf2f((unsigned short)v0[k]);
#pragma unroll
        for (int k = 0; k < 8; ++k) acc[k] += bf2f((unsigned short)v1[k]);
#pragma unroll
        for (int k = 0; k < 8; ++k) acc[k] += bf2f((unsigned short)v2[k]);
#pragma unroll
        for (int k = 0; k < 8; ++k) acc[k] += bf2f((unsigned short)v3[k]);
    }
    for (; e < end; ++e) {
        int i0 = adj[e];
        bf16x8 v0 = *(const bf16x8*)(tab + (size_t)i0 * 16);
#pragma unroll
        for (int k = 0; k < 8; ++k) acc[k] += bf2f((unsigned short)v0[k]);
    }

    int deg = end - beg;
    float inv = 1.0f / (float)(deg > 1 ? deg : 1);
    bf16x8 sv = *(const bf16x8*)(Cr + (size_t)node * 128 + s * 16 + half * 8);
    float4 b0 = ((const float4*)bias)[s * 4 + half * 2];
    float4 b1 = ((const float4*)bias)[s * 4 + half * 2 + 1];
    float bb[8] = {b0.x, b0.y, b0.z, b0.w, b1.x, b1.y, b1.z, b1.w};
    bf16x8 o;
#pragma unroll
    for (int k = 0; k < 8; ++k)
        o[k] = (short)f2bf(fmaxf(acc[k] * inv + bb[k] + bf2f((unsigned short)sv[k]), 0.f));
    *(bf16x8*)(houts + ((size_t)s * N + node) * 16 + half * 8) = o;
}

// ---------------- Final layer: 2 nodes/wave + fused log_softmax (row-major) ----

__global__ __launch_bounds__(256) void final_kernel(const unsigned short* __restrict__ Cl2,
                                                    const unsigned short* __restrict__ Cr2,
                                                    const int* __restrict__ row_ptr,
                                                    const int* __restrict__ adj,
                                                    const float* __restrict__ bias,
                                                    float* __restrict__ out, int N) {
    int pr = (int)((blockIdx.x * blockDim.x + threadIdx.x) >> 6);
    int lane = threadIdx.x & 63;
    int nodeA = pr * 2;
    if (nodeA >= N) return;
    int nodeB = nodeA + 1;
    bool hasB = nodeB < N;
    int g = lane >> 3, c = lane & 7;
    int begA = row_ptr[nodeA], endA = row_ptr[nodeA + 1];
    int begB = hasB ? row_ptr[nodeB] : 0;
    int endB = hasB ? row_ptr[nodeB + 1] : 0;
    float pA[8] = {}, pB[8] = {};

    int cntA = endA - begA; if (cntA > 64) cntA = 64;
    int cntB = endB - begB; if (cntB > 64) cntB = 64;
    int idxA = (cntA > 0) ? adj[begA + (lane < cntA ? lane : cntA - 1)] : 0;
    int idxB = (cntB > 0) ? adj[begB + (lane < cntB ? lane : cntB - 1)] : 0;
    int c1A = cntA - 1, c1B = cntB - 1;
    int mx = cntA > cntB ? cntA : cntB;
    for (int i = 0; i < mx; i += 16) {
        bool doA = i < cntA, doB = i < cntB;
        bf16x8 vA[2], vB[2];
        float mA[2], mB[2];
        if (doA) {
#pragma unroll
            for (int ss = 0; ss < 2; ++ss) {
                int tt = i + ss * 8 + g;
                int src = __shfl(idxA, tt > c1A ? c1A : tt);
                mA[ss] = tt < cntA ? 1.f : 0.f;
                vA[ss] = ((const bf16x8*)(Cl2 + (size_t)src * 64))[c];
            }
        }
        if (doB) {
#pragma unroll
            for (int ss = 0; ss < 2; ++ss) {
                int tt = i + ss * 8 + g;
                int src = __shfl(idxB, tt > c1B ? c1B : tt);
                mB[ss] = tt < cntB ? 1.f : 0.f;
                vB[ss] = ((const bf16x8*)(Cl2 + (size_t)src * 64))[c];
            }
        }
        if (doA) {
#pragma unroll
            for (int ss = 0; ss < 2; ++ss)
#pragma unroll
                for (int k = 0; k < 8; ++k)
                    pA[k] += mA[ss] * bf2f((unsigned short)vA[ss][k]);
        }
        if (doB) {
#pragma unroll
            for (int ss = 0; ss < 2; ++ss)
#pragma unroll
                for (int k = 0; k < 8; ++k)
                    pB[k] += mB[ss] * bf2f((unsigned short)vB[ss][k]);
        }
    }
    for (int e = begA + 64; e < endA; e += 64) {
        int cnt = endA - e; if (cnt > 64) cnt = 64;
        int idx = adj[e + (lane < cnt ? lane : cnt - 1)];
        int c1 = cnt - 1;
        for (int i = 0; i < cnt; i += 16) {
#pragma unroll
            for (int ss = 0; ss < 2; ++ss) {
                int tt = i + ss * 8 + g;
                int src = __shfl(idx, tt > c1 ? c1 : tt);
                float m = tt < cnt ? 1.f : 0.f;
                bf16x8 v = ((const bf16x8*)(Cl2 + (size_t)src * 64))[c];
#pragma unroll
                for (int k = 0; k < 8; ++k)
                    pA[k] += m * bf2f((unsigned short)v[k]);
            }
        }
    }
    for (int e = begB + 64; e < endB; e += 64) {
        int cnt = endB - e; if (cnt > 64) cnt = 64;
        int idx = adj[e + (lane < cnt ? lane : cnt - 1)];
        int c1 = cnt - 1;
        for (int i = 0; i < cnt; i += 16) {
#pragma unroll
            for (int ss = 0; ss < 2; ++ss) {
                int tt = i + ss * 8 + g;
                int src = __shfl(idx, tt > c1 ? c1 : tt);
                float m = tt < cnt ? 1.f : 0.f;
                bf16x8 v = ((const bf16x8*)(Cl2 + (size_t)src * 64))[c];
#pragma unroll
                for (int k = 0; k < 8; ++k)
                    pB[k] += m * bf2f((unsigned short)v[k]);
            }
        }
    }

#pragma unroll
    for (int k = 0; k < 8; ++k) {
        pA[k] += __shfl_xor(pA[k], 8);
        pA[k] += __shfl_xor(pA[k], 16);
        pA[k] += __shfl_xor(pA[k], 32);
        pB[k] += __shfl_xor(pB[k], 8);
        pB[k] += __shfl_xor(pB[k], 16);
        pB[k] += __shfl_xor(pB[k], 32);
    }

    int degA = endA - begA, degB = endB - begB;
    float invA = 1.0f / (float)(degA > 1 ? degA : 1);
    float invB = 1.0f / (float)(degB > 1 ? degB : 1);
    bf16x8 svA = ((const bf16x8*)(Cr2 + (size_t)nodeA * 64))[c];
    bf16x8 svB = hasB ? ((const bf16x8*)(Cr2 + (size_t)nodeB * 64))[c] : svA;
    float4 b0 = ((const float4*)bias)[2 * c];
    float4 b1 = ((const float4*)bias)[2 * c + 1];
    float bb[8] = {b0.x, b0.y, b0.z, b0.w, b1.x, b1.y, b1.z, b1.w};
    float uA[8], uB[8];
#pragma unroll
    for (int k = 0; k < 8; ++k) {
        uA[k] = pA[k] * invA + bb[k] + bf2f((unsigned short)svA[k]);
        uB[k] = pB[k] * invB + bb[k] + bf2f((unsigned short)svB[k]);
    }

    float mA_ = uA[0], mB_ = uB[0];
#pragma unroll
    for (int k = 1; k < 8; ++k) { mA_ = fmaxf(mA_, uA[k]); mB_ = fmaxf(mB_, uB[k]); }
#pragma unroll
    for (int off = 1; off < 8; off <<= 1) {
        mA_ = fmaxf(mA_, __shfl_xor(mA_, off));
        mB_ = fmaxf(mB_, __shfl_xor(mB_, off));
    }
    float seA = 0.f, seB = 0.f;
#pragma unroll
    for (int k = 0; k < 8; ++k) { seA += __expf(uA[k] - mA_); seB += __expf(uB[k] - mB_); }
#pragma unroll
    for (int off = 1; off < 8; off <<= 1) {
        seA += __shfl_xor(seA, off);
        seB += __shfl_xor(seB, off);
    }
    float lsA = __logf(seA), lsB = __logf(seB);

    if (g == 0) {
        float4 o0 = {uA[0] - mA_ - lsA, uA[1] - mA_ - lsA, uA[2] - mA_ - lsA, uA[3] - mA_ - lsA};
        float4 o1 = {uA[4] - mA_ - lsA, uA[5] - mA_ - lsA, uA[6] - mA_ - lsA, uA[7] - mA_ - lsA};
        ((float4*)(out + (size_t)nodeA * 64))[2 * c] = o0;
        ((float4*)(out + (size_t)nodeA * 64))[2 * c + 1] = o1;
    } else if (g == 1 && hasB) {
        float4 o0 = {uB[0] - mB_ - lsB, uB[1] - mB_ - lsB, uB[2] - mB_ - lsB, uB[3] - mB_ - lsB};
        float4 o1 = {uB[4] - mB_ - lsB, uB[5] - mB_ - lsB, uB[6] - mB_ - lsB, uB[7] - mB_ - lsB};
        ((float4*)(out + (size_t)nodeB * 64))[2 * c] = o0;
        ((float4*)(out + (size_t)nodeB * 64))[2 * c + 1] = o1;
    }
}

// ---------------- Launch ----------------

extern "C" void kernel_launch(void* const* d_in, const int* in_sizes, int n_in,
                              void* d_out, int out_size, void* d_ws, size_t ws_size,
                              hipStream_t stream) {
    const float* x   = (const float*)d_in[0];
    const int*   ei  = (const int*)d_in[1];
    const float* Wl0 = (const float*)d_in[2];
    const float* bl0 = (const float*)d_in[3];
    const float* Wr0 = (const float*)d_in[4];
    const float* Wl1 = (const float*)d_in[5];
    const float* bl1 = (const float*)d_in[6];
    const float* Wr1 = (const float*)d_in[7];
    const float* Wl2 = (const float*)d_in[8];
    const float* bl2 = (const float*)d_in[9];
    const float* Wr2 = (const float*)d_in[10];
    float* out = (float*)d_out;

    const int N  = in_sizes[0] / 128;   // 50000
    const int E  = in_sizes[1] / 2;     // 800000
    const int NB = (N + NPB - 1) / NPB; // 391 buckets

    char* ws = (char*)d_ws;
    auto alloc = [&](size_t bytes) {
        char* p = ws;
        ws += (bytes + 255) & ~(size_t)255;
        return p;
    };
    int*   row_ptr    = (int*)alloc((size_t)(N + 1) * 4);
    int*   adj        = (int*)alloc((size_t)E * 4);
    int*   gcnt      = (int*)alloc((size_t)NB * CPAD * 4);
    unsigned int* staging = (unsigned int*)alloc((size_t)NB * BCAP * 4);
    unsigned short* xbf = (unsigned short*)alloc((size_t)N * 128 * 2);
    unsigned short* wbf = (unsigned short*)alloc((size_t)81920 * 2);
    unsigned short* Cl  = (unsigned short*)alloc((size_t)N * 128 * 2);  // sliced [8][N][16] (layers 0/1) or row [N][64] (layer 2)
    unsigned short* Cr  = (unsigned short*)alloc((size_t)N * 128 * 2);
    unsigned short* hA  = (unsigned short*)alloc((size_t)N * 128 * 2);  // sliced [8][N][16]
    unsigned short* hB  = (unsigned short*)alloc((size_t)N * 128 * 2);  // sliced [8][N][16]

    const int* dstp = ei;       // edge_index row 0 = dst
    const int* srcp = ei + E;   // edge_index row 1 = src

    unsigned short* wl0 = wbf;
    unsigned short* wr0 = wbf + 16384;
    unsigned short* wl1 = wbf + 32768;
    unsigned short* wr1 = wbf + 49152;
    unsigned short* wl2 = wbf + 65536;
    unsigned short* wr2 = wbf + 73728;

    dim3 blk(256);
    int DB = (E + EPB - 1) / EPB;       // 98 distribute blocks
    int XB = (N * 64) / (256 * 4);      // 3125 x-cast blocks
    int gemmRows = (N + 127) / 128;     // 391 row-blocks of 128
    int aggSlBlocks = ((N + 127) / 128) * 8;             // 3128 (slice = bid&7)
    int pairBlocks = (((N + 1) / 2) * 64 + 255) / 256;   // 6250

    // 1) zero bucket counters
    hipMemsetAsync(gcnt, 0, (size_t)NB * CPAD * 4, stream);
    // 2) distribute + x cast + weight cast (fused)
    dist_cast_kernel<<<DB + XB + 160, blk, 0, stream>>>(dstp, srcp, gcnt, staging, E, NB,
                                                        DB, XB, x, xbf,
                                                        Wl0, Wr0, Wl1, Wr1, Wl2, Wr2, wbf);
    // 3) build + GEMM0 (xbf row-major A; Cl sliced, Cr row-major)
    build_gemm_kernel<<<NB + gemmRows * 4, blk, 0, stream>>>(staging, gcnt, row_ptr, adj,
                                                             N, NB, gemmRows, xbf, wl0, wr0,
                                                             Cl, Cr);
    // 4) agg0 (XCD-local sliced) -> hA sliced
    agg_sliced_kernel<<<aggSlBlocks, blk, 0, stream>>>(Cl, Cr, row_ptr, adj, bl0, hA, N);
    // 5) GEMM1 (A sliced; Cl sliced, Cr row-major)
    gemm_mfma_kernel<4, 1, 1><<<dim3(gemmRows, 4), blk, 0, stream>>>(hA, wl1, wr1, Cl, Cr, N);
    // 6) agg1 -> hB sliced
    agg_sliced_kernel<<<aggSlBlocks, blk, 0, stream>>>(Cl, Cr, row_ptr, adj, bl1, hB, N);
    // 7) GEMM2 (A sliced; row-major Cl2/Cr2, 64 cols each)
    gemm_mfma_kernel<2, 1, 0><<<dim3(gemmRows, 2), blk, 0, stream>>>(hB, wl2, wr2, Cl, Cr, N);
    // 8) final + log_softmax (row-gather on Cl2; self from Cr2)
    final_kernel<<<pairBlocks, blk, 0, stream>>>(Cl, Cr, row_ptr, adj, bl2, out, N);
}